// Round 11
// baseline (298.422 us; speedup 1.0000x reference)
//
#include <hip/hip_runtime.h>
#include <hip/hip_bf16.h>
#include <math.h>

typedef __attribute__((ext_vector_type(8))) short s16x8;
typedef __attribute__((ext_vector_type(4))) float f32x4;
typedef __attribute__((ext_vector_type(4))) unsigned int u32x4;

__device__ __forceinline__ unsigned short f2bf(float f) {
    unsigned int u = __float_as_uint(f);
    u += 0x7fffu + ((u >> 16) & 1u);
    return (unsigned short)(u >> 16);
}

__device__ __forceinline__ unsigned int pk2bf(float a, float b) {
    __hip_bfloat162 h = __float22bfloat162_rn(make_float2(a, b));
    return *(unsigned int*)&h;
}

// ---------------- count degree + convert weights (merged) ----------------

__global__ void count_conv_kernel(const int* __restrict__ dst, int* deg, int E,
                                  const float* __restrict__ W1, const float* __restrict__ W2,
                                  const float* __restrict__ W3, unsigned short* __restrict__ Wt1,
                                  unsigned short* __restrict__ Wt2, unsigned short* __restrict__ Wt3) {
    int i = blockIdx.x * blockDim.x + threadIdx.x;
    if (i < E) {
        atomicAdd(&deg[dst[i]], 1);
    } else {
        int w = i - E;
        if (w < 32768) {                       // 256x128
            int k = w >> 7, n = w & 127;
            Wt1[(size_t)n * 264 + k] = f2bf(W1[w]);
        } else if (w < 40960) {                // 128x64
            int j = w - 32768, k = j >> 6, n = j & 63;
            Wt2[(size_t)n * 136 + k] = f2bf(W2[j]);
        } else if (w < 43008) {                // 64x32
            int j = w - 40960, k = j >> 5, n = j & 31;
            Wt3[(size_t)n * 72 + k] = f2bf(W3[j]);
        }
    }
}

// ---------------- exclusive scan of deg -> row_ptr (+ dinv) ----------------

__global__ __launch_bounds__(256) void scan1_kernel(const int* __restrict__ deg,
                                                    int* __restrict__ row_ptr,
                                                    int* __restrict__ blockSums,
                                                    float* __restrict__ dinv, int n) {
    __shared__ int sm[256];
    int t = threadIdx.x;
    int i = blockIdx.x * 512 + 2 * t;
    int v0 = 0, v1 = 0;
    if (i < n) { v0 = deg[i]; v1 = deg[i + 1]; }  // n even
    if (i < n) {
        dinv[i] = rsqrtf((float)v0 + 1.0f);
        dinv[i + 1] = rsqrtf((float)v1 + 1.0f);
    }
    int ts = v0 + v1;
    sm[t] = ts;
    __syncthreads();
    for (int off = 1; off < 256; off <<= 1) {
        int u = (t >= off) ? sm[t - off] : 0;
        __syncthreads();
        sm[t] += u;
        __syncthreads();
    }
    int excl = sm[t] - ts;
    if (i < n) { row_ptr[i] = excl; row_ptr[i + 1] = excl + v0; }
    if (t == 255) blockSums[blockIdx.x] = sm[255];
}

__global__ __launch_bounds__(256) void scan2_kernel(const int* __restrict__ blockSums,
                                                    int* __restrict__ blockOffs, int nb) {
    __shared__ int sm[256];
    int t = threadIdx.x;
    int v = (t < nb) ? blockSums[t] : 0;
    sm[t] = v;
    __syncthreads();
    for (int off = 1; off < 256; off <<= 1) {
        int u = (t >= off) ? sm[t - off] : 0;
        __syncthreads();
        sm[t] += u;
        __syncthreads();
    }
    blockOffs[t] = sm[t] - v;
}

__global__ __launch_bounds__(256) void scan3_kernel(int* __restrict__ row_ptr,
                                                    int* __restrict__ cursor,
                                                    const int* __restrict__ blockOffs, int n) {
    int t = threadIdx.x;
    int i = blockIdx.x * 512 + 2 * t;
    int off = blockOffs[blockIdx.x];
    if (i < n) {
        int a = row_ptr[i] + off;
        int b = row_ptr[i + 1] + off;
        row_ptr[i] = a; cursor[i] = a;
        row_ptr[i + 1] = b; cursor[i + 1] = b;
    }
}

// ---------------- CSR fill: src index per edge, grouped by dst ----------------

__global__ void fill_kernel(const int* __restrict__ src, const int* __restrict__ dst,
                            int* __restrict__ cursor, int* __restrict__ pack, int E) {
    int e = blockIdx.x * blockDim.x + threadIdx.x;
    if (e < E) {
        int s = src[e], d = dst[e];
        int pos = atomicAdd(&cursor[d], 1);
        pack[pos] = s;
    }
}

// ---------------- bf16 MFMA GEMM: Z = dinv[row] * (A @ Wt), Z stored SLICE-MAJOR ----------------
// Z layout: z[(slice*M + row)*16 + c], slice = 16 output columns (3.2 MB per slice -> L2-resident).
// A: fp32 row-major (layer 1) or bf16 slice-major (layers 2/3).
// Wt pre-transposed [N][K+8] bf16 staged whole in LDS. 512 thr = 8 waves, BM=256.

__device__ __forceinline__ s16x8 cvt8(const float4& u, const float4& v) {
    union { unsigned int w[4]; s16x8 s; } cb;
    cb.w[0] = pk2bf(u.x, u.y);
    cb.w[1] = pk2bf(u.z, u.w);
    cb.w[2] = pk2bf(v.x, v.y);
    cb.w[3] = pk2bf(v.z, v.w);
    return cb.s;
}

template <int K, int N, bool ABF16>
__global__ __launch_bounds__(512) void mfma_gemm_kernel(const void* __restrict__ Av,
                                                        const unsigned short* __restrict__ Bt,
                                                        const float* __restrict__ dinv,
                                                        unsigned short* __restrict__ C, int M) {
    constexpr int KP = K + 8;
    constexpr int KSTEPS = K / 32;
    constexpr int NFRAG = N / 16;
    constexpr int BYTES = N * KP * 2;
    __shared__ unsigned short Blds[N * KP];

    int tid = threadIdx.x;
    for (int off = tid * 16; off < BYTES; off += 512 * 16)
        *(float4*)((char*)Blds + off) = *(const float4*)((const char*)Bt + off);
    __syncthreads();

    int wv = tid >> 6, lane = tid & 63;
    int r0 = blockIdx.x * 256 + wv * 32;
    int lr = lane & 15, kg = lane >> 4;
    int ra = min(r0 + lr, M - 1);
    int rb = min(r0 + 16 + lr, M - 1);

    f32x4 acc[2][NFRAG] = {};

    const float* a0f = nullptr; const float* a1f = nullptr;
    if constexpr (!ABF16) {
        a0f = (const float*)Av + (size_t)ra * K + kg * 8;
        a1f = (const float*)Av + (size_t)rb * K + kg * 8;
    }
    const unsigned short* Ab = (const unsigned short*)Av;

#pragma unroll
    for (int ks = 0; ks < KSTEPS; ++ks) {
        s16x8 a0, a1;
        if constexpr (ABF16) {
            // slice-major A: col base = kg*8 + ks*32 -> slice (kg>>1)+2*ks, offset (kg&1)*8
            int sl = (kg >> 1) + 2 * ks;
            int co = (kg & 1) * 8;
            a0 = *(const s16x8*)(Ab + ((size_t)sl * M + ra) * 16 + co);
            a1 = *(const s16x8*)(Ab + ((size_t)sl * M + rb) * 16 + co);
        } else {
            float4 u = *(const float4*)(a0f + ks * 32);
            float4 v = *(const float4*)(a0f + ks * 32 + 4);
            a0 = cvt8(u, v);
            u = *(const float4*)(a1f + ks * 32);
            v = *(const float4*)(a1f + ks * 32 + 4);
            a1 = cvt8(u, v);
        }
#pragma unroll
        for (int ni = 0; ni < NFRAG; ++ni) {
            const s16x8 b = *(const s16x8*)&Blds[(ni * 16 + lr) * KP + kg * 8 + ks * 32];
            acc[0][ni] = __builtin_amdgcn_mfma_f32_16x16x32_bf16(a0, b, acc[0][ni], 0, 0, 0);
            acc[1][ni] = __builtin_amdgcn_mfma_f32_16x16x32_bf16(a1, b, acc[1][ni], 0, 0, 0);
        }
    }

    // C/D layout: col = lane&15, row = (lane>>4)*4 + reg; scale dinv[row]; slice-major NT store
    int rbase = kg * 4;
#pragma unroll
    for (int mi = 0; mi < 2; ++mi) {
#pragma unroll
        for (int r = 0; r < 4; ++r) {
            int row = r0 + mi * 16 + rbase + r;
            if (row < M) {
                float dn = dinv[row];
#pragma unroll
                for (int ni = 0; ni < NFRAG; ++ni)
                    __builtin_nontemporal_store(
                        f2bf(acc[mi][ni][r] * dn),
                        &C[((size_t)ni * M + row) * 16 + lr]);
            }
        }
    }
}

// ---------------- XCD-sliced gather: out_slice = relu(dinv[d]*(z[d]+sum z[src]) + b) ----------------
// z slice-major; block handles slice (blockIdx & (SLICES-1)) -> pinned to one XCD by
// round-robin dispatch; slice (3.2 MB) stays L2-resident. 2 lanes per node (16 B each),
// 32 nodes per wave, 128 nodes per block.

template <int F, bool OUT_BF16>
__global__ __launch_bounds__(256) void gather_sliced_kernel(
    const unsigned short* __restrict__ z, const int* __restrict__ row_ptr,
    const int* __restrict__ deg, const int* __restrict__ pack,
    const float* __restrict__ dinv, const float* __restrict__ bias,
    void* __restrict__ outv, int N) {
    constexpr int SLICES = F / 16;
    const int b = blockIdx.x;
    const int slice = b & (SLICES - 1);
    const int chunk = b / SLICES;
    const int wv = threadIdx.x >> 6, lane = threadIdx.x & 63;
    const int wid = chunk * 128 + wv * 32 + (lane >> 1);
    if (wid >= N) return;
    const int half = lane & 1;
    const unsigned short* zs = z + (size_t)slice * N * 16 + half * 8;

    auto loadrow = [&](int node, float* y) {
        uint4 bv = *(const uint4*)(zs + (size_t)node * 16);
        y[0] = __uint_as_float(bv.x << 16);
        y[1] = __uint_as_float(bv.x & 0xffff0000u);
        y[2] = __uint_as_float(bv.y << 16);
        y[3] = __uint_as_float(bv.y & 0xffff0000u);
        y[4] = __uint_as_float(bv.z << 16);
        y[5] = __uint_as_float(bv.z & 0xffff0000u);
        y[6] = __uint_as_float(bv.w << 16);
        y[7] = __uint_as_float(bv.w & 0xffff0000u);
    };

    float acc[8], y[4][8];
    loadrow(wid, y[0]);   // self term z[d]
#pragma unroll
    for (int q = 0; q < 8; ++q) acc[q] = y[0][q];

    int beg = row_ptr[wid];
    int cnt = deg[wid];
    int j = 0;
    for (; j + 3 < cnt; j += 4) {
        int pp[4];
#pragma unroll
        for (int u = 0; u < 4; ++u) pp[u] = __builtin_nontemporal_load(&pack[beg + j + u]);
#pragma unroll
        for (int u = 0; u < 4; ++u) loadrow(pp[u], y[u]);
#pragma unroll
        for (int u = 0; u < 4; ++u) {
#pragma unroll
            for (int q = 0; q < 8; ++q) acc[q] += y[u][q];
        }
    }
    for (; j < cnt; ++j) {
        loadrow(__builtin_nontemporal_load(&pack[beg + j]), y[0]);
#pragma unroll
        for (int q = 0; q < 8; ++q) acc[q] += y[0][q];
    }

    const float dn = dinv[wid];
    const int f0 = slice * 16 + half * 8;
    float o[8];
#pragma unroll
    for (int q = 0; q < 8; ++q) o[q] = fmaxf(fmaf(dn, acc[q], bias[f0 + q]), 0.0f);

    if constexpr (OUT_BF16) {
        // slice-major bf16 output (feeds next GEMM / gather)
        u32x4 v = {pk2bf(o[0], o[1]), pk2bf(o[2], o[3]), pk2bf(o[4], o[5]), pk2bf(o[6], o[7])};
        __builtin_nontemporal_store(
            v, (u32x4*)((unsigned short*)outv + ((size_t)slice * N + wid) * 16 + half * 8));
    } else {
        // row-major fp32 final output
        float* op = (float*)outv + (size_t)wid * F + f0;
        f32x4 v0 = {o[0], o[1], o[2], o[3]};
        f32x4 v1 = {o[4], o[5], o[6], o[7]};
        __builtin_nontemporal_store(v0, (f32x4*)op);
        __builtin_nontemporal_store(v1, (f32x4*)(op + 4));
    }
}

// ---------------- launch ----------------

extern "C" void kernel_launch(void* const* d_in, const int* in_sizes, int n_in,
                              void* d_out, int out_size, void* d_ws, size_t ws_size,
                              hipStream_t stream) {
    const float* x = (const float*)d_in[0];
    const int* edge = (const int*)d_in[1];
    const float* W1 = (const float*)d_in[2];
    const float* b1 = (const float*)d_in[3];
    const float* W2 = (const float*)d_in[4];
    const float* b2 = (const float*)d_in[5];
    const float* W3 = (const float*)d_in[6];
    const float* b3 = (const float*)d_in[7];

    const int C_IN = 256, H1 = 128;
    const int N = in_sizes[0] / C_IN;   // 100000
    const int E = in_sizes[1] / 2;      // 800000
    const int* srcp = edge;
    const int* dstp = edge + E;

    // ---- workspace carve ----
    char* p = (char*)d_ws;
    size_t o = 0;
    auto alloc = [&](size_t bytes) -> void* {
        void* r = p + o;
        o = (o + bytes + 255) & ~(size_t)255;
        return r;
    };
    float* dinv      = (float*)alloc((size_t)N * 4);
    int*   deg       = (int*)alloc((size_t)N * 4);
    int*   row_ptr   = (int*)alloc((size_t)N * 4);
    int*   cursor    = (int*)alloc((size_t)N * 4);
    int*   blockSums = (int*)alloc(1024);
    int*   blockOffs = (int*)alloc(1024);
    int*   pack      = (int*)alloc((size_t)E * 4);
    unsigned short* Wt1 = (unsigned short*)alloc((size_t)128 * 264 * 2);
    unsigned short* Wt2 = (unsigned short*)alloc((size_t)64 * 136 * 2);
    unsigned short* Wt3 = (unsigned short*)alloc((size_t)32 * 72 * 2);
    unsigned short* xwb = (unsigned short*)alloc((size_t)N * H1 * 2);  // bf16 z (slice-major)
    unsigned short* act = (unsigned short*)alloc((size_t)N * H1 * 2);  // bf16 act (slice-major)
    float* out = (float*)d_out;

    const int NB = (N + 511) / 512;  // 196 <= 256

    // ---- CSR build + weight transpose/convert ----
    hipMemsetAsync(deg, 0, (size_t)N * 4, stream);
    count_conv_kernel<<<(E + 43008 + 255) / 256, 256, 0, stream>>>(dstp, deg, E, W1, W2, W3,
                                                                   Wt1, Wt2, Wt3);
    scan1_kernel<<<NB, 256, 0, stream>>>(deg, row_ptr, blockSums, dinv, N);
    scan2_kernel<<<1, 256, 0, stream>>>(blockSums, blockOffs, NB);
    scan3_kernel<<<NB, 256, 0, stream>>>(row_ptr, cursor, blockOffs, N);
    fill_kernel<<<(E + 255) / 256, 256, 0, stream>>>(srcp, dstp, cursor, pack, E);

    const int GEMM_BLOCKS = (N + 255) / 256;
    const int CHUNKS = (N + 127) / 128;

    // ---- layer 1: 256 -> 128 ----
    mfma_gemm_kernel<256, 128, false><<<GEMM_BLOCKS, 512, 0, stream>>>(x, Wt1, dinv, xwb, N);
    gather_sliced_kernel<128, true><<<CHUNKS * 8, 256, 0, stream>>>(xwb, row_ptr, deg, pack,
                                                                    dinv, b1, act, N);
    // ---- layer 2: 128 -> 64 ----
    mfma_gemm_kernel<128, 64, true><<<GEMM_BLOCKS, 512, 0, stream>>>(act, Wt2, dinv, xwb, N);
    gather_sliced_kernel<64, true><<<CHUNKS * 4, 256, 0, stream>>>(xwb, row_ptr, deg, pack,
                                                                   dinv, b2, act, N);
    // ---- layer 3: 64 -> 32 ----
    mfma_gemm_kernel<64, 32, true><<<GEMM_BLOCKS, 512, 0, stream>>>(act, Wt3, dinv, xwb, N);
    gather_sliced_kernel<32, false><<<CHUNKS * 2, 256, 0, stream>>>(xwb, row_ptr, deg, pack,
                                                                    dinv, b3, out, N);
}

// Round 12
// 212.734 us; speedup vs baseline: 1.4028x; 1.4028x over previous
//
#include <hip/hip_runtime.h>
#include <hip/hip_bf16.h>
#include <math.h>

typedef __attribute__((ext_vector_type(8))) short s16x8;
typedef __attribute__((ext_vector_type(4))) float f32x4;

__device__ __forceinline__ unsigned short f2bf(float f) {
    unsigned int u = __float_as_uint(f);
    u += 0x7fffu + ((u >> 16) & 1u);
    return (unsigned short)(u >> 16);
}

__device__ __forceinline__ unsigned int pk2bf(float a, float b) {
    __hip_bfloat162 h = __float22bfloat162_rn(make_float2(a, b));
    return *(unsigned int*)&h;
}

// ---------------- zero deg + convert all weights (one dispatch) ----------------

__global__ void zero_conv_kernel(int* __restrict__ deg, int N,
                                 const float* __restrict__ W1, const float* __restrict__ W2,
                                 const float* __restrict__ W3, unsigned short* __restrict__ Wt1,
                                 unsigned short* __restrict__ Wt2, unsigned short* __restrict__ Wt3) {
    int i = blockIdx.x * blockDim.x + threadIdx.x;
    if (i < N) deg[i] = 0;
    if (i < 32768) {                       // 256x128
        int k = i >> 7, n = i & 127;
        Wt1[(size_t)n * 264 + k] = f2bf(W1[i]);
    } else if (i < 40960) {                // 128x64
        int j = i - 32768, k = j >> 6, n = j & 63;
        Wt2[(size_t)n * 136 + k] = f2bf(W2[j]);
    } else if (i < 43008) {                // 64x32
        int j = i - 40960, k = j >> 5, n = j & 31;
        Wt3[(size_t)n * 72 + k] = f2bf(W3[j]);
    }
}

// ---------------- layer-1 GEMM (fp32 A) + edge degree count in trailing blocks ----------------
// C_bf16[M,128] = A_f32[M,256] @ Wt1; blocks >= GB do the degree count instead.

__device__ __forceinline__ s16x8 cvt8(const float4& u, const float4& v) {
    union { unsigned int w[4]; s16x8 s; } cb;
    cb.w[0] = pk2bf(u.x, u.y);
    cb.w[1] = pk2bf(u.z, u.w);
    cb.w[2] = pk2bf(v.x, v.y);
    cb.w[3] = pk2bf(v.z, v.w);
    return cb.s;
}

__global__ __launch_bounds__(512) void gemm1_count_kernel(const float* __restrict__ A,
                                                          const unsigned short* __restrict__ Bt,
                                                          unsigned short* __restrict__ C, int M,
                                                          int GB, const int* __restrict__ dst,
                                                          int* __restrict__ deg, int E) {
    constexpr int K = 256, N = 128, KP = K + 8, KSTEPS = K / 32, NFRAG = N / 16;
    __shared__ unsigned short Blds[N * KP];

    if (blockIdx.x >= GB) {   // ---- degree-count blocks (overlap with GEMM) ----
        int i = (blockIdx.x - GB) * 512 + threadIdx.x;
        if (i < E) atomicAdd(&deg[dst[i]], 1);
        return;
    }

    int tid = threadIdx.x;
    for (int off = tid * 16; off < N * KP * 2; off += 512 * 16)
        *(float4*)((char*)Blds + off) = *(const float4*)((const char*)Bt + off);
    __syncthreads();

    int wv = tid >> 6, lane = tid & 63;
    int r0 = blockIdx.x * 256 + wv * 32;
    int lr = lane & 15, kg = lane >> 4;
    int ra = min(r0 + lr, M - 1);
    int rb = min(r0 + 16 + lr, M - 1);

    f32x4 acc[2][NFRAG] = {};
    const float* a0f = A + (size_t)ra * K + kg * 8;
    const float* a1f = A + (size_t)rb * K + kg * 8;

#pragma unroll
    for (int ks = 0; ks < KSTEPS; ++ks) {
        float4 u = *(const float4*)(a0f + ks * 32);
        float4 v = *(const float4*)(a0f + ks * 32 + 4);
        s16x8 a0 = cvt8(u, v);
        u = *(const float4*)(a1f + ks * 32);
        v = *(const float4*)(a1f + ks * 32 + 4);
        s16x8 a1 = cvt8(u, v);
#pragma unroll
        for (int ni = 0; ni < NFRAG; ++ni) {
            const s16x8 b = *(const s16x8*)&Blds[(ni * 16 + lr) * KP + kg * 8 + ks * 32];
            acc[0][ni] = __builtin_amdgcn_mfma_f32_16x16x32_bf16(a0, b, acc[0][ni], 0, 0, 0);
            acc[1][ni] = __builtin_amdgcn_mfma_f32_16x16x32_bf16(a1, b, acc[1][ni], 0, 0, 0);
        }
    }

    int rbase = kg * 4;
#pragma unroll
    for (int mi = 0; mi < 2; ++mi) {
#pragma unroll
        for (int r = 0; r < 4; ++r) {
            int row = r0 + mi * 16 + rbase + r;
            if (row < M) {
#pragma unroll
                for (int ni = 0; ni < NFRAG; ++ni)
                    C[(size_t)row * N + ni * 16 + lr] = f2bf(acc[mi][ni][r]);
            }
        }
    }
}

// ---------------- scan1: block-local exclusive scan of deg (+ dinv) ----------------

__global__ __launch_bounds__(256) void scan1_kernel(const int* __restrict__ deg,
                                                    int* __restrict__ row_ptr,
                                                    int* __restrict__ blockSums,
                                                    float* __restrict__ dinv, int n) {
    __shared__ int sm[256];
    int t = threadIdx.x;
    int i = blockIdx.x * 512 + 2 * t;
    int v0 = 0, v1 = 0;
    if (i < n) { v0 = deg[i]; v1 = deg[i + 1]; }  // n even
    if (i < n) {
        dinv[i] = rsqrtf((float)v0 + 1.0f);
        dinv[i + 1] = rsqrtf((float)v1 + 1.0f);
    }
    int ts = v0 + v1;
    sm[t] = ts;
    __syncthreads();
    for (int off = 1; off < 256; off <<= 1) {
        int u = (t >= off) ? sm[t - off] : 0;
        __syncthreads();
        sm[t] += u;
        __syncthreads();
    }
    int excl = sm[t] - ts;
    if (i < n) { row_ptr[i] = excl; row_ptr[i + 1] = excl + v0; }
    if (t == 255) blockSums[blockIdx.x] = sm[255];
}

// ---------------- scan23: redundant scan of blockSums + apply -> row_ptr, cursor ----------------

__global__ __launch_bounds__(256) void scan23_kernel(int* __restrict__ row_ptr,
                                                     int* __restrict__ cursor,
                                                     const int* __restrict__ blockSums,
                                                     int nb, int n) {
    __shared__ int sm[256];
    int t = threadIdx.x;
    int v = (t < nb) ? blockSums[t] : 0;
    sm[t] = v;
    __syncthreads();
    for (int off = 1; off < 256; off <<= 1) {
        int u = (t >= off) ? sm[t - off] : 0;
        __syncthreads();
        sm[t] += u;
        __syncthreads();
    }
    // exclusive offset for this block
    __shared__ int boff;
    if (t == 0) boff = (blockIdx.x == 0) ? 0 : sm[blockIdx.x - 1];
    __syncthreads();
    int off = boff;
    int i = blockIdx.x * 512 + 2 * t;
    if (i < n) {
        int a = row_ptr[i] + off;
        int b = row_ptr[i + 1] + off;
        row_ptr[i] = a; cursor[i] = a;
        row_ptr[i + 1] = b; cursor[i + 1] = b;
    }
}

// ---------------- CSR fill: pack (src, coef) per edge, grouped by dst ----------------

__global__ void fill_kernel(const int* __restrict__ src, const int* __restrict__ dst,
                            const float* __restrict__ dinv, int* __restrict__ cursor,
                            int2* __restrict__ pack, int E) {
    int e = blockIdx.x * blockDim.x + threadIdx.x;
    if (e < E) {
        int s = src[e], d = dst[e];
        int pos = atomicAdd(&cursor[d], 1);
        pack[pos] = make_int2(s, __float_as_int(dinv[s] * dinv[d]));
    }
}

// ---------------- shared gather core: o[VPL] = relu(agg_row + bias) ----------------

template <int F, int VPL>
__device__ __forceinline__ void gather_node(const unsigned short* __restrict__ xw,
                                            const int* __restrict__ row_ptr,
                                            const int* __restrict__ deg,
                                            const int2* __restrict__ pack,
                                            const float* __restrict__ dinv,
                                            const float* __restrict__ bias,
                                            int wid, int f0, float* o) {
    auto loadrow = [&](const unsigned short* r, float* y) {
        if constexpr (VPL == 8) {
            uint4 b = *(const uint4*)(r + f0);
            y[0] = __uint_as_float(b.x << 16);
            y[1] = __uint_as_float(b.x & 0xffff0000u);
            y[2] = __uint_as_float(b.y << 16);
            y[3] = __uint_as_float(b.y & 0xffff0000u);
            y[4] = __uint_as_float(b.z << 16);
            y[5] = __uint_as_float(b.z & 0xffff0000u);
            y[6] = __uint_as_float(b.w << 16);
            y[7] = __uint_as_float(b.w & 0xffff0000u);
        } else if constexpr (VPL == 4) {
            uint2 b = *(const uint2*)(r + f0);
            y[0] = __uint_as_float(b.x << 16);
            y[1] = __uint_as_float(b.x & 0xffff0000u);
            y[2] = __uint_as_float(b.y << 16);
            y[3] = __uint_as_float(b.y & 0xffff0000u);
        } else {
            unsigned int b = *(const unsigned int*)(r + f0);
            y[0] = __uint_as_float(b << 16);
            y[1] = __uint_as_float(b & 0xffff0000u);
        }
    };

    float dn = dinv[wid];
    float acc[VPL], y[8][VPL];
    loadrow(xw + (size_t)wid * F, y[0]);
#pragma unroll
    for (int q = 0; q < VPL; ++q) acc[q] = y[0][q] * dn * dn;

    int beg = row_ptr[wid];
    int cnt = deg[wid];
    int j = 0;
    for (; j + 7 < cnt; j += 8) {
        int2 pp[8];
#pragma unroll
        for (int u = 0; u < 8; ++u) pp[u] = pack[beg + j + u];
#pragma unroll
        for (int u = 0; u < 8; ++u) loadrow(xw + (size_t)pp[u].x * F, y[u]);
#pragma unroll
        for (int u = 0; u < 8; ++u) {
            float c = __int_as_float(pp[u].y);
#pragma unroll
            for (int q = 0; q < VPL; ++q) acc[q] += y[u][q] * c;
        }
    }
    for (; j + 3 < cnt; j += 4) {
        int2 pp[4];
#pragma unroll
        for (int u = 0; u < 4; ++u) pp[u] = pack[beg + j + u];
#pragma unroll
        for (int u = 0; u < 4; ++u) loadrow(xw + (size_t)pp[u].x * F, y[u]);
#pragma unroll
        for (int u = 0; u < 4; ++u) {
            float c = __int_as_float(pp[u].y);
#pragma unroll
            for (int q = 0; q < VPL; ++q) acc[q] += y[u][q] * c;
        }
    }
    for (; j < cnt; ++j) {
        int2 p0 = pack[beg + j];
        loadrow(xw + (size_t)p0.x * F, y[0]);
        float c0 = __int_as_float(p0.y);
#pragma unroll
        for (int q = 0; q < VPL; ++q) acc[q] += y[0][q] * c0;
    }

#pragma unroll
    for (int q = 0; q < VPL; ++q) o[q] = fmaxf(acc[q] + bias[f0 + q], 0.0f);
}

// ---------------- bf16 MFMA GEMM (layers 2/3): C_bf16[M,N] = A_bf16[M,K] @ Wt ----------------

template <int K, int N>
__global__ __launch_bounds__(512) void mfma_gemm_kernel(const unsigned short* __restrict__ A,
                                                        const unsigned short* __restrict__ Bt,
                                                        unsigned short* __restrict__ C, int M) {
    constexpr int KP = K + 8;
    constexpr int KSTEPS = K / 32;
    constexpr int NFRAG = N / 16;
    __shared__ unsigned short Blds[N * KP];

    int tid = threadIdx.x;
    for (int off = tid * 16; off < N * KP * 2; off += 512 * 16)
        *(float4*)((char*)Blds + off) = *(const float4*)((const char*)Bt + off);
    __syncthreads();

    int wv = tid >> 6, lane = tid & 63;
    int r0 = blockIdx.x * 256 + wv * 32;
    int lr = lane & 15, kg = lane >> 4;
    int ra = min(r0 + lr, M - 1);
    int rb = min(r0 + 16 + lr, M - 1);

    f32x4 acc[2][NFRAG] = {};
    const unsigned short* a0h = A + (size_t)ra * K + kg * 8;
    const unsigned short* a1h = A + (size_t)rb * K + kg * 8;

#pragma unroll
    for (int ks = 0; ks < KSTEPS; ++ks) {
        s16x8 a0 = *(const s16x8*)(a0h + ks * 32);
        s16x8 a1 = *(const s16x8*)(a1h + ks * 32);
#pragma unroll
        for (int ni = 0; ni < NFRAG; ++ni) {
            const s16x8 b = *(const s16x8*)&Blds[(ni * 16 + lr) * KP + kg * 8 + ks * 32];
            acc[0][ni] = __builtin_amdgcn_mfma_f32_16x16x32_bf16(a0, b, acc[0][ni], 0, 0, 0);
            acc[1][ni] = __builtin_amdgcn_mfma_f32_16x16x32_bf16(a1, b, acc[1][ni], 0, 0, 0);
        }
    }

    int rbase = kg * 4;
#pragma unroll
    for (int mi = 0; mi < 2; ++mi) {
#pragma unroll
        for (int r = 0; r < 4; ++r) {
            int row = r0 + mi * 16 + rbase + r;
            if (row < M) {
#pragma unroll
                for (int ni = 0; ni < NFRAG; ++ni)
                    C[(size_t)row * N + ni * 16 + lr] = f2bf(acc[mi][ni][r]);
            }
        }
    }
}

// ---------------- standalone gather ----------------

template <int F, int GPW, int VPL, bool OUT_BF16>
__global__ __launch_bounds__(256) void gather_kernel(const unsigned short* __restrict__ xw,
                                                     const int* __restrict__ row_ptr,
                                                     const int* __restrict__ deg,
                                                     const int2* __restrict__ pack,
                                                     const float* __restrict__ dinv,
                                                     const float* __restrict__ bias,
                                                     void* __restrict__ outv, int N) {
    constexpr int LPG = 64 / GPW;
    static_assert(LPG * VPL == F, "lane layout must cover F");
    int wave = blockIdx.x * 4 + (threadIdx.x >> 6);
    int lane = threadIdx.x & 63;
    int wid = wave * GPW + lane / LPG;
    int gl = lane % LPG;
    if (wid >= N) return;
    const int f0 = gl * VPL;

    float o[VPL];
    gather_node<F, VPL>(xw, row_ptr, deg, pack, dinv, bias, wid, f0, o);

    if constexpr (OUT_BF16) {
        unsigned short* op = (unsigned short*)outv + (size_t)wid * F + f0;
        if constexpr (VPL == 8) {
            *(uint4*)op = make_uint4(pk2bf(o[0], o[1]), pk2bf(o[2], o[3]),
                                     pk2bf(o[4], o[5]), pk2bf(o[6], o[7]));
        } else if constexpr (VPL == 4) {
            *(uint2*)op = make_uint2(pk2bf(o[0], o[1]), pk2bf(o[2], o[3]));
        } else {
            *(unsigned int*)op = pk2bf(o[0], o[1]);
        }
    } else {
        float* op = (float*)outv + (size_t)wid * F + f0;
        if constexpr (VPL == 4) {
            *(float4*)op = make_float4(o[0], o[1], o[2], o[3]);
        } else {
            *(float2*)op = make_float2(o[0], o[1]);
        }
    }
}

// ---------------- launch ----------------

extern "C" void kernel_launch(void* const* d_in, const int* in_sizes, int n_in,
                              void* d_out, int out_size, void* d_ws, size_t ws_size,
                              hipStream_t stream) {
    const float* x = (const float*)d_in[0];
    const int* edge = (const int*)d_in[1];
    const float* W1 = (const float*)d_in[2];
    const float* b1 = (const float*)d_in[3];
    const float* W2 = (const float*)d_in[4];
    const float* b2 = (const float*)d_in[5];
    const float* W3 = (const float*)d_in[6];
    const float* b3 = (const float*)d_in[7];

    const int C_IN = 256, H1 = 128;
    const int N = in_sizes[0] / C_IN;   // 100000
    const int E = in_sizes[1] / 2;      // 800000
    const int* srcp = edge;
    const int* dstp = edge + E;

    // ---- workspace carve ----
    char* p = (char*)d_ws;
    size_t o = 0;
    auto alloc = [&](size_t bytes) -> void* {
        void* r = p + o;
        o = (o + bytes + 255) & ~(size_t)255;
        return r;
    };
    float* dinv      = (float*)alloc((size_t)N * 4);
    int*   deg       = (int*)alloc((size_t)N * 4);
    int*   row_ptr   = (int*)alloc((size_t)N * 4);
    int*   cursor    = (int*)alloc((size_t)N * 4);
    int*   blockSums = (int*)alloc(1024);
    int2*  pack      = (int2*)alloc((size_t)E * 8);
    unsigned short* Wt1 = (unsigned short*)alloc((size_t)128 * 264 * 2);
    unsigned short* Wt2 = (unsigned short*)alloc((size_t)64 * 136 * 2);
    unsigned short* Wt3 = (unsigned short*)alloc((size_t)32 * 72 * 2);
    unsigned short* xwb = (unsigned short*)alloc((size_t)N * H1 * 2);  // bf16 xw
    unsigned short* act = (unsigned short*)alloc((size_t)N * H1 * 2);  // bf16 activations
    float* out = (float*)d_out;

    const int NB = (N + 511) / 512;      // 196 <= 256
    const int GEMM_BLOCKS = (N + 255) / 256;
    const int COUNT_BLOCKS = (E + 511) / 512;

    // ---- zero deg + convert weights (one dispatch) ----
    zero_conv_kernel<<<(N + 255) / 256, 256, 0, stream>>>(deg, N, W1, W2, W3, Wt1, Wt2, Wt3);

    // ---- layer-1 GEMM with degree count overlapped in trailing blocks ----
    gemm1_count_kernel<<<GEMM_BLOCKS + COUNT_BLOCKS, 512, 0, stream>>>(
        x, Wt1, xwb, N, GEMM_BLOCKS, dstp, deg, E);

    // ---- CSR scan + fill ----
    scan1_kernel<<<NB, 256, 0, stream>>>(deg, row_ptr, blockSums, dinv, N);
    scan23_kernel<<<NB, 256, 0, stream>>>(row_ptr, cursor, blockSums, NB, N);
    fill_kernel<<<(E + 255) / 256, 256, 0, stream>>>(srcp, dstp, dinv, cursor, pack, E);

    // ---- layer 1 gather ----
    gather_kernel<128, 4, 8, true><<<(N + 15) / 16, 256, 0, stream>>>(xwb, row_ptr, deg, pack, dinv, b1, act, N);
    // ---- layer 2 ----
    mfma_gemm_kernel<128, 64><<<GEMM_BLOCKS, 512, 0, stream>>>(act, Wt2, xwb, N);
    gather_kernel<64, 4, 4, true><<<(N + 15) / 16, 256, 0, stream>>>(xwb, row_ptr, deg, pack, dinv, b2, act, N);
    // ---- layer 3 ----
    mfma_gemm_kernel<64, 32><<<GEMM_BLOCKS, 512, 0, stream>>>(act, Wt3, xwb, N);
    gather_kernel<32, 4, 2, false><<<(N + 15) / 16, 256, 0, stream>>>(xwb, row_ptr, deg, pack, dinv, b3, out, N);
}